// Round 1
// 58.994 us; speedup vs baseline: 1.0337x; 1.0337x over previous
//
#include <hip/hip_runtime.h>

// Problem: B=64, M=64, P=128, V=32. Output = 0.5 * min_{m,p} dist(last_point[63,m], poly[63,p])
// Only batch index 63 contributes (reference takes per_batch_min[-1]).
//
// Single fused launch: 128 blocks (one per polygon) x 64 threads (one per point).
// Each block writes a validity-tagged partial min {bits^MAGIC, bits} as one atomic u64;
// block 0 spin-waits on all 128 tags, reduces, writes the scalar output.
// Tag scheme is init-free: any repeated-byte ws poison has hi==lo, which can never
// equal hi == lo ^ MAGIC for MAGIC != 0.
#define BNUM 64
#define MNUM 64
#define PNUM 128
#define VNUM 32
#define EPSF 1e-12f
#define MAGIC 0x9E3779B9u

__global__ void __launch_bounds__(64) poly_loss_fused(
        const float* __restrict__ last_point,           // [B, M, 2]
        const float* __restrict__ polygon_coords,       // [B, P, V, 2]
        unsigned long long* __restrict__ ws64,          // [P] tagged partials
        float* __restrict__ out)                        // scalar
{
    const int p = blockIdx.x;   // 0..127
    const int m = threadIdx.x;  // 0..63

    // Point for batch 63, point m.
    const float px = last_point[((BNUM - 1) * MNUM + m) * 2 + 0];
    const float py = last_point[((BNUM - 1) * MNUM + m) * 2 + 1];

    // Polygon verts for batch 63, polygon p -> LDS (tiny, broadcast-read later).
    __shared__ float vx[VNUM], vy[VNUM];
    const float* poly = polygon_coords + (size_t)(((BNUM - 1) * PNUM + p) * VNUM) * 2;
    if (m < VNUM) {
        vx[m] = poly[m * 2 + 0];
        vy[m] = poly[m * 2 + 1];
    }
    __syncthreads();

    float min_d2 = 3.4e38f;
    int crossings = 0;
    #pragma unroll
    for (int v = 0; v < VNUM; ++v) {
        const float ax = vx[v],            ay = vy[v];
        const float bx = vx[(v + 1) & 31], by = vy[(v + 1) & 31];
        const float abx = bx - ax, aby = by - ay;
        const float apx = px - ax, apy = py - ay;

        // t = clip(dot(ap,ab)/(dot(ab,ab)+EPS), 0, 1)
        float t = (apx * abx + apy * aby) / (abx * abx + aby * aby + EPSF);
        t = fminf(fmaxf(t, 0.0f), 1.0f);
        const float dx = apx - t * abx;
        const float dy = apy - t * aby;
        min_d2 = fminf(min_d2, dx * dx + dy * dy);

        // ray-crossing parity: straddles & (px < x_int)
        const bool straddle = (ay > py) != (by > py);
        const float x_int = ax + abx * apy / (aby + EPSF);
        crossings += (straddle && (px < x_int)) ? 1 : 0;
    }

    // sqrt hoisted out of the loop: min(sqrt(max(d2,EPS))) == sqrt(max(min(d2),EPS))
    // exactly (correctly-rounded sqrt is monotone; max-with-const commutes with min).
    float dist = (crossings & 1) ? 0.0f : sqrtf(fmaxf(min_d2, EPSF));

    // wave-64 min reduction
    #pragma unroll
    for (int off = 32; off > 0; off >>= 1)
        dist = fminf(dist, __shfl_down(dist, off, 64));

    if (m == 0) {
        const unsigned int bits = __float_as_uint(dist);
        const unsigned long long pk =
            ((unsigned long long)(bits ^ MAGIC) << 32) | (unsigned long long)bits;
        __hip_atomic_store(&ws64[p], pk, __ATOMIC_RELEASE, __HIP_MEMORY_SCOPE_AGENT);
    }

    // Block 0 gathers all 128 partials. Each lane polls slots m and m+64.
    // 128 blocks on 256 CUs are always co-resident -> spin cannot deadlock.
    if (p == 0) {
        float a, b;
        for (;;) {
            const unsigned long long x =
                __hip_atomic_load(&ws64[m], __ATOMIC_ACQUIRE, __HIP_MEMORY_SCOPE_AGENT);
            if ((unsigned int)(x >> 32) == ((unsigned int)x ^ MAGIC)) {
                a = __uint_as_float((unsigned int)x);
                break;
            }
        }
        for (;;) {
            const unsigned long long x =
                __hip_atomic_load(&ws64[m + 64], __ATOMIC_ACQUIRE, __HIP_MEMORY_SCOPE_AGENT);
            if ((unsigned int)(x >> 32) == ((unsigned int)x ^ MAGIC)) {
                b = __uint_as_float((unsigned int)x);
                break;
            }
        }
        float vmin = fminf(a, b);
        #pragma unroll
        for (int off = 32; off > 0; off >>= 1)
            vmin = fminf(vmin, __shfl_down(vmin, off, 64));
        if (m == 0) out[0] = 0.5f * vmin;
    }
}

extern "C" void kernel_launch(void* const* d_in, const int* in_sizes, int n_in,
                              void* d_out, int out_size, void* d_ws, size_t ws_size,
                              hipStream_t stream) {
    const float* last_point     = (const float*)d_in[0]; // [64,64,2]
    const float* polygon_coords = (const float*)d_in[1]; // [64,128,32,2]

    poly_loss_fused<<<dim3(PNUM), dim3(64), 0, stream>>>(
        last_point, polygon_coords, (unsigned long long*)d_ws, (float*)d_out);
}

// Round 2
// 58.671 us; speedup vs baseline: 1.0394x; 1.0055x over previous
//
#include <hip/hip_runtime.h>

// Problem: B=64, M=64, P=128, V=32. Output = 0.5 * min_{m,p} dist(last_point[63,m], poly[63,p])
// Only batch index 63 contributes (reference takes per_batch_min[-1]).
//
// Single fused launch: 128 blocks (one per polygon) x 64 threads (one per point).
// Polygon verts are block-uniform -> loaded via scalar loads (no LDS, no barrier).
// Each block writes a validity-tagged partial min {bits^MAGIC, bits} as one atomic u64;
// the LAST-dispatched block (p=127) spin-waits on all 128 tags, reduces, writes out.
// Tag scheme is init-free: any repeated-byte ws poison has hi==lo, which can never
// equal hi == lo ^ MAGIC for MAGIC != 0.
#define BNUM 64
#define MNUM 64
#define PNUM 128
#define VNUM 32
#define EPSF 1e-12f
#define MAGIC 0x9E3779B9u

__global__ void __launch_bounds__(64) poly_loss_fused(
        const float* __restrict__ last_point,           // [B, M, 2]
        const float* __restrict__ polygon_coords,       // [B, P, V, 2]
        unsigned long long* __restrict__ ws64,          // [P] tagged partials
        float* __restrict__ out)                        // scalar
{
    const int p = blockIdx.x;   // 0..127
    const int m = threadIdx.x;  // 0..63

    // Point for batch 63, point m — one coalesced 8B load per lane.
    const float2 pt = reinterpret_cast<const float2*>(last_point)[(BNUM - 1) * MNUM + m];
    const float px = pt.x, py = pt.y;

    // Polygon verts for batch 63, polygon p. Address depends only on blockIdx ->
    // wave-uniform -> compiler emits scalar (s_load) broadcasts. No LDS, no sync.
    const float2* __restrict__ poly =
        reinterpret_cast<const float2*>(polygon_coords) + (size_t)((BNUM - 1) * PNUM + p) * VNUM;
    float vx[VNUM], vy[VNUM];
    #pragma unroll
    for (int v = 0; v < VNUM; ++v) {
        const float2 vert = poly[v];
        vx[v] = vert.x;
        vy[v] = vert.y;
    }

    float min_d2 = 3.4e38f;
    int crossings = 0;
    #pragma unroll
    for (int v = 0; v < VNUM; ++v) {
        const float ax = vx[v],            ay = vy[v];
        const float bx = vx[(v + 1) & 31], by = vy[(v + 1) & 31];
        const float abx = bx - ax, aby = by - ay;
        const float apx = px - ax, apy = py - ay;

        // t = clip(dot(ap,ab)/(dot(ab,ab)+EPS), 0, 1)
        float t = (apx * abx + apy * aby) / (abx * abx + aby * aby + EPSF);
        t = fminf(fmaxf(t, 0.0f), 1.0f);
        const float dx = apx - t * abx;
        const float dy = apy - t * aby;
        min_d2 = fminf(min_d2, dx * dx + dy * dy);

        // ray-crossing parity: straddles & (px < x_int)
        const bool straddle = (ay > py) != (by > py);
        const float x_int = ax + abx * apy / (aby + EPSF);
        crossings += (straddle && (px < x_int)) ? 1 : 0;
    }

    // sqrt hoisted out of the loop: min(sqrt(max(d2,EPS))) == sqrt(max(min(d2),EPS))
    // exactly (correctly-rounded sqrt is monotone; max-with-const commutes with min).
    float dist = (crossings & 1) ? 0.0f : sqrtf(fmaxf(min_d2, EPSF));

    // wave-64 min reduction
    #pragma unroll
    for (int off = 32; off > 0; off >>= 1)
        dist = fminf(dist, __shfl_down(dist, off, 64));

    if (m == 0) {
        const unsigned int bits = __float_as_uint(dist);
        const unsigned long long pk =
            ((unsigned long long)(bits ^ MAGIC) << 32) | (unsigned long long)bits;
        __hip_atomic_store(&ws64[p], pk, __ATOMIC_RELEASE, __HIP_MEMORY_SCOPE_AGENT);
    }

    // Last-dispatched block gathers all 128 partials: by the time it gets here the
    // other 127 blocks (dispatched earlier onto 256 idle CUs) have typically already
    // stored, so the spin retires in ~1 poll round. Each lane polls slots m and m+64
    // concurrently. 128 blocks on 256 CUs are always co-resident -> no deadlock.
    if (p == PNUM - 1) {
        float a = 0.0f, b = 0.0f;
        bool va = false, vb = false;
        do {
            if (!va) {
                const unsigned long long x =
                    __hip_atomic_load(&ws64[m], __ATOMIC_ACQUIRE, __HIP_MEMORY_SCOPE_AGENT);
                if ((unsigned int)(x >> 32) == ((unsigned int)x ^ MAGIC)) {
                    a = __uint_as_float((unsigned int)x);
                    va = true;
                }
            }
            if (!vb) {
                const unsigned long long x =
                    __hip_atomic_load(&ws64[m + 64], __ATOMIC_ACQUIRE, __HIP_MEMORY_SCOPE_AGENT);
                if ((unsigned int)(x >> 32) == ((unsigned int)x ^ MAGIC)) {
                    b = __uint_as_float((unsigned int)x);
                    vb = true;
                }
            }
        } while (!(va && vb));
        float vmin = fminf(a, b);
        #pragma unroll
        for (int off = 32; off > 0; off >>= 1)
            vmin = fminf(vmin, __shfl_down(vmin, off, 64));
        if (m == 0) out[0] = 0.5f * vmin;
    }
}

extern "C" void kernel_launch(void* const* d_in, const int* in_sizes, int n_in,
                              void* d_out, int out_size, void* d_ws, size_t ws_size,
                              hipStream_t stream) {
    const float* last_point     = (const float*)d_in[0]; // [64,64,2]
    const float* polygon_coords = (const float*)d_in[1]; // [64,128,32,2]

    poly_loss_fused<<<dim3(PNUM), dim3(64), 0, stream>>>(
        last_point, polygon_coords, (unsigned long long*)d_ws, (float*)d_out);
}